// Round 4
// baseline (3282.318 us; speedup 1.0000x reference)
//
#include <hip/hip_runtime.h>
#include <math.h>

#define NSEG 533
#define CFEAT 2112
#define PIX 160000
#define SIM_THRESH 0.97f
#define KC 16   // segsum k-chunks

typedef __attribute__((ext_vector_type(4))) float f32x4;
typedef __attribute__((ext_vector_type(4))) int   i32x4;
typedef __attribute__((ext_vector_type(8))) short bf16x8;

__device__ inline unsigned short f2bf_u16(float f) {
    unsigned u = __builtin_bit_cast(unsigned, f);
    return (unsigned short)((u + 0x7FFFu + ((u >> 16) & 1u)) >> 16);
}
__device__ inline unsigned pkbf(float a, float b) {   // low=bf16(a), high=bf16(b)
    unsigned r;
    asm("v_cvt_pk_bf16_f32 %0, %1, %2" : "=v"(r) : "v"(a), "v"(b));
    return r;
}

// K1: per-segment label histogram (y in {0,1,2})
__global__ __launch_bounds__(256) void k_counts(const int* __restrict__ sp,
                                                const int* __restrict__ y,
                                                int* __restrict__ c3) {
    int p = blockIdx.x * 256 + threadIdx.x;
    if (p < PIX) atomicAdd(&c3[sp[p] * 3 + y[p]], 1);
}

// K2: majority label + tie-break, writes lab/labeled outputs
__global__ __launch_bounds__(256) void k_labels(const int* __restrict__ c3,
                                                int* __restrict__ lab,
                                                float* __restrict__ invc,
                                                float* __restrict__ out) {
    int s = blockIdx.x * 256 + threadIdx.x;
    if (s >= NSEG) return;
    int c0 = c3[s * 3 + 0], c1 = c3[s * 3 + 1], c2 = c3[s * 3 + 2];
    int cnt = c0 + c1 + c2;
    int idx = 0, best = c0;
    if (c1 > best) { best = c1; idx = 1; }
    if (c2 > best) { best = c2; idx = 2; }
    if (idx == 0) idx = (c2 > c1) ? 2 : ((c1 > c2) ? 1 : 0);
    lab[s] = idx;
    invc[s] = 1.0f / (float)(cnt > 0 ? cnt : 1);
    out[1066 + s] = (float)idx;
    out[1599 + s] = (idx != 0) ? 1.0f : 0.0f;
}

// K3: segment sums as onehot-MFMA GEMM, v3 (occupancy-first).
// Wave = 32 segs (2 Mtiles) x 64 ch (4 Ntiles): acc = 32 AGPR, ~130 unified
// regs -> 3-4 waves/SIMD. Block = 8 waves = 256 segs sharing the same B
// (L1-absorbed); grid = (3 seg-blocks, 33 ch-groups, KC k-chunks).
__global__ __launch_bounds__(512) void k_segsum_mfma(const float* __restrict__ fm,
                                                     const int* __restrict__ sp,
                                                     float* __restrict__ sums) {
    const int lane = threadIdx.x & 63;
    const int wave = threadIdx.x >> 6;        // 0..7
    const int wg = blockIdx.x * 8 + wave;     // seg wave-group (32 segs each)
    if (wg >= 17) return;
    const int r = lane & 15, kg = lane >> 4;
    const int c0 = blockIdx.y * 64;
    const int sbase = wg * 32;

    const int bstep = (int)(((long long)blockIdx.z * (PIX / 32)) / KC);
    const int estep = (int)(((long long)(blockIdx.z + 1) * (PIX / 32)) / KC);
    const int nst = estep - bstep;

    const float* bp0 = fm + (size_t)(c0 + r) * PIX + (size_t)bstep * 32 + kg * 8;
    const float* bp1 = bp0 + (size_t)16 * PIX;
    const float* bp2 = bp0 + (size_t)32 * PIX;
    const float* bp3 = bp0 + (size_t)48 * PIX;
    const int* spp = sp + (size_t)bstep * 32 + kg * 8;

    f32x4 acc[2][4] = {};

    i32x4 sA = *(const i32x4*)spp;            // sp double-buffer
    i32x4 sB = *(const i32x4*)(spp + 4);

    for (int st = 0; st < nst; ++st) {
        const size_t o = (size_t)st * 32;
        // issue B loads first (latency overlapped by A-build below)
        f32x4 f0 = *(const f32x4*)(bp0 + o);
        f32x4 f1 = *(const f32x4*)(bp0 + o + 4);
        f32x4 f2 = *(const f32x4*)(bp1 + o);
        f32x4 f3 = *(const f32x4*)(bp1 + o + 4);
        f32x4 f4 = *(const f32x4*)(bp2 + o);
        f32x4 f5 = *(const f32x4*)(bp2 + o + 4);
        f32x4 f6 = *(const f32x4*)(bp3 + o);
        f32x4 f7 = *(const f32x4*)(bp3 + o + 4);
        i32x4 s0 = sA, s1 = sB;
        if (st + 1 < nst) {
            sA = *(const i32x4*)(spp + o + 32);
            sB = *(const i32x4*)(spp + o + 36);
        }
        int seg[8] = { s0[0], s0[1], s0[2], s0[3], s1[0], s1[1], s1[2], s1[3] };

        // A-build: pure VALU on already-resident seg values
        unsigned aw[2][4];
        #pragma unroll
        for (int i = 0; i < 2; ++i) {
            const int tgt = sbase + i * 16 + r;
            #pragma unroll
            for (int t = 0; t < 4; ++t) {
                aw[i][t] = ((seg[2 * t]     == tgt) ? 0x00003F80u : 0u) |
                           ((seg[2 * t + 1] == tgt) ? 0x3F800000u : 0u);
            }
        }

        // pack B: 32 f32 -> 16 packed bf16 words
        uint4 wb0 = { pkbf(f0[0], f0[1]), pkbf(f0[2], f0[3]), pkbf(f1[0], f1[1]), pkbf(f1[2], f1[3]) };
        uint4 wb1 = { pkbf(f2[0], f2[1]), pkbf(f2[2], f2[3]), pkbf(f3[0], f3[1]), pkbf(f3[2], f3[3]) };
        uint4 wb2 = { pkbf(f4[0], f4[1]), pkbf(f4[2], f4[3]), pkbf(f5[0], f5[1]), pkbf(f5[2], f5[3]) };
        uint4 wb3 = { pkbf(f6[0], f6[1]), pkbf(f6[2], f6[3]), pkbf(f7[0], f7[1]), pkbf(f7[2], f7[3]) };
        bf16x8 vb0 = __builtin_bit_cast(bf16x8, wb0);
        bf16x8 vb1 = __builtin_bit_cast(bf16x8, wb1);
        bf16x8 vb2 = __builtin_bit_cast(bf16x8, wb2);
        bf16x8 vb3 = __builtin_bit_cast(bf16x8, wb3);

        #pragma unroll
        for (int i = 0; i < 2; ++i) {
            uint4 w4 = { aw[i][0], aw[i][1], aw[i][2], aw[i][3] };
            bf16x8 va = __builtin_bit_cast(bf16x8, w4);
            acc[i][0] = __builtin_amdgcn_mfma_f32_16x16x32_bf16(va, vb0, acc[i][0], 0, 0, 0);
            acc[i][1] = __builtin_amdgcn_mfma_f32_16x16x32_bf16(va, vb1, acc[i][1], 0, 0, 0);
            acc[i][2] = __builtin_amdgcn_mfma_f32_16x16x32_bf16(va, vb2, acc[i][2], 0, 0, 0);
            acc[i][3] = __builtin_amdgcn_mfma_f32_16x16x32_bf16(va, vb3, acc[i][3], 0, 0, 0);
        }
    }

    // flush: C/D col(channel)=r, row(segment)=kg*4+q  (rows 533..543 are
    // always-zero scratch rows; sums has 544 rows allocated)
    #pragma unroll
    for (int i = 0; i < 2; ++i) {
        #pragma unroll
        for (int nt = 0; nt < 4; ++nt) {
            #pragma unroll
            for (int q = 0; q < 4; ++q) {
                int s = sbase + i * 16 + kg * 4 + q;
                unsafeAtomicAdd(&sums[(size_t)s * CFEAT + c0 + nt * 16 + r],
                                acc[i][nt][q]);
            }
        }
    }
}

// K4: mean (in place) + bf16 copy + inverse row norm
__global__ __launch_bounds__(256) void k_mean(float* __restrict__ feat,
                                              unsigned short* __restrict__ featbf,
                                              const float* __restrict__ invc,
                                              float* __restrict__ invn) {
    int s = blockIdx.x;
    float ic = invc[s];
    float ss = 0.0f;
    for (int c = threadIdx.x; c < CFEAT; c += 256) {
        float v = feat[(size_t)s * CFEAT + c] * ic;
        feat[(size_t)s * CFEAT + c] = v;
        featbf[(size_t)s * CFEAT + c] = f2bf_u16(v);
        ss += v * v;
    }
    __shared__ float red[256];
    red[threadIdx.x] = ss;
    __syncthreads();
    for (int st = 128; st > 0; st >>= 1) {
        if (threadIdx.x < st) red[threadIdx.x] += red[threadIdx.x + st];
        __syncthreads();
    }
    if (threadIdx.x == 0) invn[s] = 1.0f / fmaxf(sqrtf(red[0]), 1e-12f);
}

// Transpose + f32->bf16 convert: outT[n][k] = bf16(in[k][n]). Dims mult of 32.
__global__ __launch_bounds__(256) void k_cvtT(const float* __restrict__ in,
                                              unsigned short* __restrict__ outT,
                                              int K, int N) {
    __shared__ float s[32][33];
    int n0 = blockIdx.x * 32, k0 = blockIdx.y * 32;
    int lx = threadIdx.x & 31, ly = threadIdx.x >> 5;   // ly 0..7
    #pragma unroll
    for (int p = 0; p < 4; ++p)
        s[ly + p * 8][lx] = in[(size_t)(k0 + ly + p * 8) * N + n0 + lx];
    __syncthreads();
    #pragma unroll
    for (int p = 0; p < 4; ++p)
        outT[(size_t)(n0 + ly + p * 8) * K + k0 + lx] = f2bf_u16(s[lx][ly + p * 8]);
}

// bf16 MFMA GEMM: C[M][N] = act(A[M][K] @ Bt[N][K]^T + bias).
// 64x64 tile, BK=64, 4 waves (wave = M-quarter). XOR-swizzled LDS.
template <int RELU>
__global__ __launch_bounds__(256) void gemm_bf16(const unsigned short* __restrict__ A,
                                                 const unsigned short* __restrict__ Bt,
                                                 const float* __restrict__ bias,
                                                 float* __restrict__ Cf,
                                                 unsigned short* __restrict__ Cb,
                                                 int M, int N, int K) {
    __shared__ char As[64 * 128];
    __shared__ char Bs[64 * 128];
    const int tid = threadIdx.x;
    const int lane = tid & 63, wave = tid >> 6;
    const int r = lane & 15, kg = lane >> 4;
    const int m0 = blockIdx.y * 64, n0 = blockIdx.x * 64;
    const int row = tid >> 2, colw = tid & 3;   // staging role
    const int swz = (row & 7) << 4;
    f32x4 acc[4] = {};

    for (int k0 = 0; k0 < K; k0 += 64) {
        {   // stage A (row-guarded)
            uint4 v0 = {}, v1 = {};
            if (m0 + row < M) {
                const unsigned short* src = A + (size_t)(m0 + row) * K + k0 + colw * 16;
                v0 = *(const uint4*)src;
                v1 = *(const uint4*)(src + 8);
            }
            *(uint4*)(As + row * 128 + ((colw * 32) ^ swz)) = v0;
            *(uint4*)(As + row * 128 + ((colw * 32 + 16) ^ swz)) = v1;
        }
        {   // stage Bt
            uint4 v0 = {}, v1 = {};
            if (n0 + row < N) {
                const unsigned short* src = Bt + (size_t)(n0 + row) * K + k0 + colw * 16;
                v0 = *(const uint4*)src;
                v1 = *(const uint4*)(src + 8);
            }
            *(uint4*)(Bs + row * 128 + ((colw * 32) ^ swz)) = v0;
            *(uint4*)(Bs + row * 128 + ((colw * 32 + 16) ^ swz)) = v1;
        }
        __syncthreads();
        #pragma unroll
        for (int ks = 0; ks < 2; ++ks) {
            const int arow = wave * 16 + r;
            bf16x8 va = *(const bf16x8*)(As + arow * 128 + (((ks * 64) + kg * 16) ^ ((arow & 7) << 4)));
            #pragma unroll
            for (int nt = 0; nt < 4; ++nt) {
                const int brow = nt * 16 + r;
                bf16x8 vb = *(const bf16x8*)(Bs + brow * 128 + (((ks * 64) + kg * 16) ^ ((brow & 7) << 4)));
                acc[nt] = __builtin_amdgcn_mfma_f32_16x16x32_bf16(va, vb, acc[nt], 0, 0, 0);
            }
        }
        __syncthreads();
    }

    #pragma unroll
    for (int nt = 0; nt < 4; ++nt) {
        #pragma unroll
        for (int q = 0; q < 4; ++q) {
            int gr = m0 + wave * 16 + kg * 4 + q;
            int gc = n0 + nt * 16 + r;
            if (gr < M && gc < N) {
                float v = acc[nt][q];
                if (bias) v += bias[gc];
                if (RELU) v = fmaxf(v, 0.0f);
                if (Cf) Cf[(size_t)gr * N + gc] = v;
                if (Cb) Cb[(size_t)gr * N + gc] = f2bf_u16(v);
            }
        }
    }
}

// K6: masked row-max/argmax over affinity + label propagation
__global__ __launch_bounds__(256) void k_prop(const float* __restrict__ aff,
                                              const int* __restrict__ lab,
                                              const float* __restrict__ invn,
                                              float* __restrict__ out) {
    int i = blockIdx.x;
    float invi = invn[i];
    float best = -INFINITY;
    int bidx = 0;
    for (int j = threadIdx.x; j < NSEG; j += 256) {
        if (lab[j] != 0) {
            float v = aff[(size_t)i * NSEG + j] * invi * invn[j];
            if (v > best) { best = v; bidx = j; }
        }
    }
    __shared__ float bv[256];
    __shared__ int bi[256];
    bv[threadIdx.x] = best;
    bi[threadIdx.x] = bidx;
    __syncthreads();
    for (int st = 128; st > 0; st >>= 1) {
        if (threadIdx.x < st) {
            float v2 = bv[threadIdx.x + st];
            int i2 = bi[threadIdx.x + st];
            if (v2 > bv[threadIdx.x] ||
                (v2 == bv[threadIdx.x] && i2 < bi[threadIdx.x])) {
                bv[threadIdx.x] = v2;
                bi[threadIdx.x] = i2;
            }
        }
        __syncthreads();
    }
    if (threadIdx.x == 0) {
        int li = lab[i];
        int nl = li;
        if (li == 0 && bv[0] >= SIM_THRESH) nl = lab[bi[0]];
        out[2132 + i] = (float)nl;
    }
}

// K7: final 32->2 head + softmax -> preds
__global__ __launch_bounds__(256) void k_head(const float* __restrict__ h3,
                                              const float* __restrict__ wc,
                                              const float* __restrict__ bc,
                                              float* __restrict__ out) {
    int s = blockIdx.x * 256 + threadIdx.x;
    if (s >= NSEG) return;
    float z0 = bc[0], z1 = bc[1];
    #pragma unroll
    for (int k = 0; k < 32; k++) {
        float h = h3[s * 32 + k];
        z0 += h * wc[k * 2 + 0];
        z1 += h * wc[k * 2 + 1];
    }
    float m = fmaxf(z0, z1);
    float e0 = expf(z0 - m), e1 = expf(z1 - m);
    float inv = 1.0f / (e0 + e1);
    out[s * 2 + 0] = e0 * inv;
    out[s * 2 + 1] = e1 * inv;
}

extern "C" void kernel_launch(void* const* d_in, const int* in_sizes, int n_in,
                              void* d_out, int out_size, void* d_ws, size_t ws_size,
                              hipStream_t stream) {
    const float* fm = (const float*)d_in[0];
    const int* sp   = (const int*)d_in[1];
    const int* y    = (const int*)d_in[2];
    const float* w1 = (const float*)d_in[3];
    const float* b1 = (const float*)d_in[4];
    const float* w2 = (const float*)d_in[5];
    const float* b2 = (const float*)d_in[6];
    const float* w3 = (const float*)d_in[7];
    const float* b3 = (const float*)d_in[8];
    const float* wc = (const float*)d_in[9];
    const float* bc = (const float*)d_in[10];
    float* out = (float*)d_out;
    char* ws = (char*)d_ws;

    size_t off = 0;
    auto alloc = [&](size_t bytes) {
        size_t o = off;
        off += (bytes + 255) & ~(size_t)255;
        return o;
    };
    float*          feat   = (float*)(ws + alloc((size_t)544 * CFEAT * 4));
    unsigned short* featbf = (unsigned short*)(ws + alloc((size_t)544 * CFEAT * 2));
    unsigned short* w1T    = (unsigned short*)(ws + alloc((size_t)1024 * CFEAT * 2));
    unsigned short* w2T    = (unsigned short*)(ws + alloc((size_t)1024 * 1024 * 2));
    unsigned short* w3T    = (unsigned short*)(ws + alloc((size_t)32 * 1024 * 2));
    unsigned short* h1bf   = (unsigned short*)(ws + alloc((size_t)544 * 1024 * 2));
    unsigned short* h2bf   = (unsigned short*)(ws + alloc((size_t)544 * 1024 * 2));
    float*          h3     = (float*)(ws + alloc((size_t)544 * 32 * 4));
    float*          aff    = (float*)(ws + alloc((size_t)NSEG * NSEG * 4));
    int*            c3     = (int*)(ws + alloc((size_t)NSEG * 3 * 4));
    int*            lab    = (int*)(ws + alloc((size_t)NSEG * 4));
    float*          invc   = (float*)(ws + alloc((size_t)NSEG * 4));
    float*          invn   = (float*)(ws + alloc((size_t)NSEG * 4));

    hipMemsetAsync(feat, 0, (size_t)544 * CFEAT * 4, stream);
    hipMemsetAsync(c3, 0, (size_t)NSEG * 3 * 4, stream);

    // one-off weight transpose+convert (independent of segsum)
    k_cvtT<<<dim3(1024 / 32, CFEAT / 32), 256, 0, stream>>>(w1, w1T, CFEAT, 1024);
    k_cvtT<<<dim3(1024 / 32, 1024 / 32), 256, 0, stream>>>(w2, w2T, 1024, 1024);
    k_cvtT<<<dim3(32 / 32, 1024 / 32), 256, 0, stream>>>(w3, w3T, 1024, 32);

    k_counts<<<(PIX + 255) / 256, 256, 0, stream>>>(sp, y, c3);
    k_labels<<<3, 256, 0, stream>>>(c3, lab, invc, out);
    k_segsum_mfma<<<dim3(3, 33, KC), 512, 0, stream>>>(fm, sp, feat);
    k_mean<<<NSEG, 256, 0, stream>>>(feat, featbf, invc, invn);

    gemm_bf16<1><<<dim3(16, 9), 256, 0, stream>>>(featbf, w1T, b1, nullptr, h1bf, NSEG, 1024, CFEAT);
    gemm_bf16<1><<<dim3(16, 9), 256, 0, stream>>>(h1bf, w2T, b2, nullptr, h2bf, NSEG, 1024, 1024);
    gemm_bf16<1><<<dim3(1, 9), 256, 0, stream>>>(h2bf, w3T, b3, h3, nullptr, NSEG, 32, 1024);
    gemm_bf16<0><<<dim3(9, 9), 256, 0, stream>>>(featbf, featbf, nullptr, aff, nullptr, NSEG, NSEG, CFEAT);

    k_head<<<3, 256, 0, stream>>>(h3, wc, bc, out);
    k_prop<<<NSEG, 256, 0, stream>>>(aff, lab, invn, out);
}

// Round 5
// 684.313 us; speedup vs baseline: 4.7965x; 4.7965x over previous
//
#include <hip/hip_runtime.h>
#include <math.h>

#define NSEG 533
#define CFEAT 2112
#define PIX 160000
#define SIM_THRESH 0.97f
#define RPG 1250            // 128-px rounds per ch-group
#define NCG 33              // ch-groups of 64
#define RTOT (RPG * NCG)    // 41250 round-tasks
#define NBLK 256

typedef __attribute__((ext_vector_type(4))) float f32x4;
typedef __attribute__((ext_vector_type(4))) int   i32x4;
typedef __attribute__((ext_vector_type(8))) short bf16x8;

__device__ inline unsigned short f2bf_u16(float f) {
    unsigned u = __builtin_bit_cast(unsigned, f);
    return (unsigned short)((u + 0x7FFFu + ((u >> 16) & 1u)) >> 16);
}
__device__ inline unsigned pkbf(float a, float b) {   // low=bf16(a), high=bf16(b)
    unsigned r;
    asm("v_cvt_pk_bf16_f32 %0, %1, %2" : "=v"(r) : "v"(a), "v"(b));
    return r;
}

// K1: per-segment label histogram (y in {0,1,2})
__global__ __launch_bounds__(256) void k_counts(const int* __restrict__ sp,
                                                const int* __restrict__ y,
                                                int* __restrict__ c3) {
    int p = blockIdx.x * 256 + threadIdx.x;
    if (p < PIX) atomicAdd(&c3[sp[p] * 3 + y[p]], 1);
}

// K2: majority label + tie-break, writes lab/labeled outputs
__global__ __launch_bounds__(256) void k_labels(const int* __restrict__ c3,
                                                int* __restrict__ lab,
                                                float* __restrict__ invc,
                                                float* __restrict__ out) {
    int s = blockIdx.x * 256 + threadIdx.x;
    if (s >= NSEG) return;
    int c0 = c3[s * 3 + 0], c1 = c3[s * 3 + 1], c2 = c3[s * 3 + 2];
    int cnt = c0 + c1 + c2;
    int idx = 0, best = c0;
    if (c1 > best) { best = c1; idx = 1; }
    if (c2 > best) { best = c2; idx = 2; }
    if (idx == 0) idx = (c2 > c1) ? 2 : ((c1 > c2) ? 1 : 0);
    lab[s] = idx;
    invc[s] = 1.0f / (float)(cnt > 0 ? cnt : 1);
    out[1066 + s] = (float)idx;
    out[1599 + s] = (idx != 0) ? 1.0f : 0.0f;
}

// K3 v4: onehot-MFMA segsum, LDS-shared B.
// Block = 16 waves (1024 thr) covering ALL 34 M-tiles (waves own {3,3,2,...})
// x 64 channels. B (64ch x 128px, packed bf16) staged per round into
// double-buffered LDS with the proven XOR-swizzled layout; fm read ONCE.
// Grid = 256 flat blocks, equal contiguous slices of (cg, round) task space.
__global__ __launch_bounds__(1024, 4) void k_segsum_mfma(const float* __restrict__ fm,
                                                         const int* __restrict__ sp,
                                                         float* __restrict__ sums) {
    __shared__ char Bs[2][64 * 256];
    const int tid = threadIdx.x;
    const int lane = tid & 63, wave = tid >> 6;      // wave 0..15
    const int r = lane & 15, kg = lane >> 4;
    const int nmt = (wave < 2) ? 3 : 2;              // M-tiles this wave owns
    const int rswz = (r & 7) << 4;                   // read-side XOR
    // staging role: channel sch, px chunk spx (8 px = 32B f32 = 16B bf16)
    const int sch = tid >> 4;                        // 0..63
    const int spx = tid & 15;                        // 0..15
    const int wswz = (sch & 7) << 4;

    long long t0 = ((long long)blockIdx.x * RTOT) / NBLK;
    const long long t1 = ((long long)(blockIdx.x + 1) * RTOT) / NBLK;

    while (t0 < t1) {
        const int cg = (int)(t0 / RPG);
        const int r0 = (int)(t0 - (long long)cg * RPG);
        const long long cgend = (long long)(cg + 1) * RPG;
        const int rend = (int)(((t1 < cgend) ? t1 : cgend) - (long long)cg * RPG);
        const int c0 = cg * 64;
        const float* fmg = fm + (size_t)(c0 + sch) * PIX;

        f32x4 acc[3][4] = {};

        {   // stage round r0
            const float* src = fmg + r0 * 128 + spx * 8;
            f32x4 u0 = *(const f32x4*)src;
            f32x4 u1 = *(const f32x4*)(src + 4);
            uint4 w = { pkbf(u0[0], u0[1]), pkbf(u0[2], u0[3]),
                        pkbf(u1[0], u1[1]), pkbf(u1[2], u1[3]) };
            *(uint4*)(Bs[r0 & 1] + sch * 256 + ((spx * 16) ^ wswz)) = w;
        }
        __syncthreads();

        for (int rr = r0; rr < rend; ++rr) {
            const bool pf = (rr + 1 < rend);
            f32x4 u0 = {}, u1 = {};
            if (pf) {   // issue next round's global loads early (T14)
                const float* src = fmg + (rr + 1) * 128 + spx * 8;
                u0 = *(const f32x4*)src;
                u1 = *(const f32x4*)(src + 4);
            }
            const char* bufc = Bs[rr & 1];
            const int* spr = sp + rr * 128 + kg * 8;
            i32x4 sa = *(const i32x4*)spr;
            i32x4 sb = *(const i32x4*)(spr + 4);

            #pragma unroll
            for (int ks = 0; ks < 4; ++ks) {
                i32x4 na, nb;
                if (ks < 3) {   // prefetch next ks's sp (L1 broadcast)
                    na = *(const i32x4*)(spr + (ks + 1) * 32);
                    nb = *(const i32x4*)(spr + (ks + 1) * 32 + 4);
                }
                // B fragments from LDS (zero-conflict pattern)
                bf16x8 vb[4];
                #pragma unroll
                for (int nt = 0; nt < 4; ++nt) {
                    vb[nt] = *(const bf16x8*)(bufc + (nt * 16 + r) * 256 +
                                              ((ks * 64 + kg * 16) ^ rswz));
                }
                int seg[8] = { sa[0], sa[1], sa[2], sa[3], sb[0], sb[1], sb[2], sb[3] };
                #pragma unroll
                for (int i = 0; i < 3; ++i) {
                    if (i < nmt) {
                        const int tm = (i < 2) ? wave * 2 + i : 32 + wave;
                        const int tgt = tm * 16 + r;
                        unsigned w0 = ((seg[0] == tgt) ? 0x00003F80u : 0u) |
                                      ((seg[1] == tgt) ? 0x3F800000u : 0u);
                        unsigned w1 = ((seg[2] == tgt) ? 0x00003F80u : 0u) |
                                      ((seg[3] == tgt) ? 0x3F800000u : 0u);
                        unsigned w2 = ((seg[4] == tgt) ? 0x00003F80u : 0u) |
                                      ((seg[5] == tgt) ? 0x3F800000u : 0u);
                        unsigned w3 = ((seg[6] == tgt) ? 0x00003F80u : 0u) |
                                      ((seg[7] == tgt) ? 0x3F800000u : 0u);
                        uint4 w4 = { w0, w1, w2, w3 };
                        bf16x8 va = __builtin_bit_cast(bf16x8, w4);
                        acc[i][0] = __builtin_amdgcn_mfma_f32_16x16x32_bf16(va, vb[0], acc[i][0], 0, 0, 0);
                        acc[i][1] = __builtin_amdgcn_mfma_f32_16x16x32_bf16(va, vb[1], acc[i][1], 0, 0, 0);
                        acc[i][2] = __builtin_amdgcn_mfma_f32_16x16x32_bf16(va, vb[2], acc[i][2], 0, 0, 0);
                        acc[i][3] = __builtin_amdgcn_mfma_f32_16x16x32_bf16(va, vb[3], acc[i][3], 0, 0, 0);
                    }
                }
                if (ks < 3) { sa = na; sb = nb; }
            }

            if (pf) {   // pack + write next round's buffer
                uint4 w = { pkbf(u0[0], u0[1]), pkbf(u0[2], u0[3]),
                            pkbf(u1[0], u1[1]), pkbf(u1[2], u1[3]) };
                *(uint4*)(Bs[(rr + 1) & 1] + sch * 256 + ((spx * 16) ^ wswz)) = w;
            }
            __syncthreads();
        }

        // flush this cg-chunk: C/D col(ch)=r, row(seg)=kg*4+q
        #pragma unroll
        for (int i = 0; i < 3; ++i) {
            if (i < nmt) {
                const int tm = (i < 2) ? wave * 2 + i : 32 + wave;
                #pragma unroll
                for (int nt = 0; nt < 4; ++nt) {
                    #pragma unroll
                    for (int q = 0; q < 4; ++q) {
                        int s = tm * 16 + kg * 4 + q;
                        unsafeAtomicAdd(&sums[(size_t)s * CFEAT + c0 + nt * 16 + r],
                                        acc[i][nt][q]);
                    }
                }
            }
        }
        t0 = (t1 < cgend) ? t1 : cgend;
        if (t0 < t1) __syncthreads();   // LDS reuse across cg-chunks
    }
}

// K4: mean (in place) + bf16 copy + inverse row norm
__global__ __launch_bounds__(256) void k_mean(float* __restrict__ feat,
                                              unsigned short* __restrict__ featbf,
                                              const float* __restrict__ invc,
                                              float* __restrict__ invn) {
    int s = blockIdx.x;
    float ic = invc[s];
    float ss = 0.0f;
    for (int c = threadIdx.x; c < CFEAT; c += 256) {
        float v = feat[(size_t)s * CFEAT + c] * ic;
        feat[(size_t)s * CFEAT + c] = v;
        featbf[(size_t)s * CFEAT + c] = f2bf_u16(v);
        ss += v * v;
    }
    __shared__ float red[256];
    red[threadIdx.x] = ss;
    __syncthreads();
    for (int st = 128; st > 0; st >>= 1) {
        if (threadIdx.x < st) red[threadIdx.x] += red[threadIdx.x + st];
        __syncthreads();
    }
    if (threadIdx.x == 0) invn[s] = 1.0f / fmaxf(sqrtf(red[0]), 1e-12f);
}

// Transpose + f32->bf16 convert: outT[n][k] = bf16(in[k][n]). Dims mult of 32.
__global__ __launch_bounds__(256) void k_cvtT(const float* __restrict__ in,
                                              unsigned short* __restrict__ outT,
                                              int K, int N) {
    __shared__ float s[32][33];
    int n0 = blockIdx.x * 32, k0 = blockIdx.y * 32;
    int lx = threadIdx.x & 31, ly = threadIdx.x >> 5;   // ly 0..7
    #pragma unroll
    for (int p = 0; p < 4; ++p)
        s[ly + p * 8][lx] = in[(size_t)(k0 + ly + p * 8) * N + n0 + lx];
    __syncthreads();
    #pragma unroll
    for (int p = 0; p < 4; ++p)
        outT[(size_t)(n0 + ly + p * 8) * K + k0 + lx] = f2bf_u16(s[lx][ly + p * 8]);
}

// bf16 MFMA GEMM: C[M][N] = act(A[M][K] @ Bt[N][K]^T + bias).
// 64x64 tile, BK=64, 4 waves (wave = M-quarter). XOR-swizzled LDS.
template <int RELU>
__global__ __launch_bounds__(256) void gemm_bf16(const unsigned short* __restrict__ A,
                                                 const unsigned short* __restrict__ Bt,
                                                 const float* __restrict__ bias,
                                                 float* __restrict__ Cf,
                                                 unsigned short* __restrict__ Cb,
                                                 int M, int N, int K) {
    __shared__ char As[64 * 128];
    __shared__ char Bs[64 * 128];
    const int tid = threadIdx.x;
    const int lane = tid & 63, wave = tid >> 6;
    const int r = lane & 15, kg = lane >> 4;
    const int m0 = blockIdx.y * 64, n0 = blockIdx.x * 64;
    const int row = tid >> 2, colw = tid & 3;   // staging role
    const int swz = (row & 7) << 4;
    f32x4 acc[4] = {};

    for (int k0 = 0; k0 < K; k0 += 64) {
        {   // stage A (row-guarded)
            uint4 v0 = {}, v1 = {};
            if (m0 + row < M) {
                const unsigned short* src = A + (size_t)(m0 + row) * K + k0 + colw * 16;
                v0 = *(const uint4*)src;
                v1 = *(const uint4*)(src + 8);
            }
            *(uint4*)(As + row * 128 + ((colw * 32) ^ swz)) = v0;
            *(uint4*)(As + row * 128 + ((colw * 32 + 16) ^ swz)) = v1;
        }
        {   // stage Bt
            uint4 v0 = {}, v1 = {};
            if (n0 + row < N) {
                const unsigned short* src = Bt + (size_t)(n0 + row) * K + k0 + colw * 16;
                v0 = *(const uint4*)src;
                v1 = *(const uint4*)(src + 8);
            }
            *(uint4*)(Bs + row * 128 + ((colw * 32) ^ swz)) = v0;
            *(uint4*)(Bs + row * 128 + ((colw * 32 + 16) ^ swz)) = v1;
        }
        __syncthreads();
        #pragma unroll
        for (int ks = 0; ks < 2; ++ks) {
            const int arow = wave * 16 + r;
            bf16x8 va = *(const bf16x8*)(As + arow * 128 + (((ks * 64) + kg * 16) ^ ((arow & 7) << 4)));
            #pragma unroll
            for (int nt = 0; nt < 4; ++nt) {
                const int brow = nt * 16 + r;
                bf16x8 vb = *(const bf16x8*)(Bs + brow * 128 + (((ks * 64) + kg * 16) ^ ((brow & 7) << 4)));
                acc[nt] = __builtin_amdgcn_mfma_f32_16x16x32_bf16(va, vb, acc[nt], 0, 0, 0);
            }
        }
        __syncthreads();
    }

    #pragma unroll
    for (int nt = 0; nt < 4; ++nt) {
        #pragma unroll
        for (int q = 0; q < 4; ++q) {
            int gr = m0 + wave * 16 + kg * 4 + q;
            int gc = n0 + nt * 16 + r;
            if (gr < M && gc < N) {
                float v = acc[nt][q];
                if (bias) v += bias[gc];
                if (RELU) v = fmaxf(v, 0.0f);
                if (Cf) Cf[(size_t)gr * N + gc] = v;
                if (Cb) Cb[(size_t)gr * N + gc] = f2bf_u16(v);
            }
        }
    }
}

// K6: masked row-max/argmax over affinity + label propagation
__global__ __launch_bounds__(256) void k_prop(const float* __restrict__ aff,
                                              const int* __restrict__ lab,
                                              const float* __restrict__ invn,
                                              float* __restrict__ out) {
    int i = blockIdx.x;
    float invi = invn[i];
    float best = -INFINITY;
    int bidx = 0;
    for (int j = threadIdx.x; j < NSEG; j += 256) {
        if (lab[j] != 0) {
            float v = aff[(size_t)i * NSEG + j] * invi * invn[j];
            if (v > best) { best = v; bidx = j; }
        }
    }
    __shared__ float bv[256];
    __shared__ int bi[256];
    bv[threadIdx.x] = best;
    bi[threadIdx.x] = bidx;
    __syncthreads();
    for (int st = 128; st > 0; st >>= 1) {
        if (threadIdx.x < st) {
            float v2 = bv[threadIdx.x + st];
            int i2 = bi[threadIdx.x + st];
            if (v2 > bv[threadIdx.x] ||
                (v2 == bv[threadIdx.x] && i2 < bi[threadIdx.x])) {
                bv[threadIdx.x] = v2;
                bi[threadIdx.x] = i2;
            }
        }
        __syncthreads();
    }
    if (threadIdx.x == 0) {
        int li = lab[i];
        int nl = li;
        if (li == 0 && bv[0] >= SIM_THRESH) nl = lab[bi[0]];
        out[2132 + i] = (float)nl;
    }
}

// K7: final 32->2 head + softmax -> preds
__global__ __launch_bounds__(256) void k_head(const float* __restrict__ h3,
                                              const float* __restrict__ wc,
                                              const float* __restrict__ bc,
                                              float* __restrict__ out) {
    int s = blockIdx.x * 256 + threadIdx.x;
    if (s >= NSEG) return;
    float z0 = bc[0], z1 = bc[1];
    #pragma unroll
    for (int k = 0; k < 32; k++) {
        float h = h3[s * 32 + k];
        z0 += h * wc[k * 2 + 0];
        z1 += h * wc[k * 2 + 1];
    }
    float m = fmaxf(z0, z1);
    float e0 = expf(z0 - m), e1 = expf(z1 - m);
    float inv = 1.0f / (e0 + e1);
    out[s * 2 + 0] = e0 * inv;
    out[s * 2 + 1] = e1 * inv;
}

extern "C" void kernel_launch(void* const* d_in, const int* in_sizes, int n_in,
                              void* d_out, int out_size, void* d_ws, size_t ws_size,
                              hipStream_t stream) {
    const float* fm = (const float*)d_in[0];
    const int* sp   = (const int*)d_in[1];
    const int* y    = (const int*)d_in[2];
    const float* w1 = (const float*)d_in[3];
    const float* b1 = (const float*)d_in[4];
    const float* w2 = (const float*)d_in[5];
    const float* b2 = (const float*)d_in[6];
    const float* w3 = (const float*)d_in[7];
    const float* b3 = (const float*)d_in[8];
    const float* wc = (const float*)d_in[9];
    const float* bc = (const float*)d_in[10];
    float* out = (float*)d_out;
    char* ws = (char*)d_ws;

    size_t off = 0;
    auto alloc = [&](size_t bytes) {
        size_t o = off;
        off += (bytes + 255) & ~(size_t)255;
        return o;
    };
    float*          feat   = (float*)(ws + alloc((size_t)544 * CFEAT * 4));
    unsigned short* featbf = (unsigned short*)(ws + alloc((size_t)544 * CFEAT * 2));
    unsigned short* w1T    = (unsigned short*)(ws + alloc((size_t)1024 * CFEAT * 2));
    unsigned short* w2T    = (unsigned short*)(ws + alloc((size_t)1024 * 1024 * 2));
    unsigned short* w3T    = (unsigned short*)(ws + alloc((size_t)32 * 1024 * 2));
    unsigned short* h1bf   = (unsigned short*)(ws + alloc((size_t)544 * 1024 * 2));
    unsigned short* h2bf   = (unsigned short*)(ws + alloc((size_t)544 * 1024 * 2));
    float*          h3     = (float*)(ws + alloc((size_t)544 * 32 * 4));
    float*          aff    = (float*)(ws + alloc((size_t)NSEG * NSEG * 4));
    int*            c3     = (int*)(ws + alloc((size_t)NSEG * 3 * 4));
    int*            lab    = (int*)(ws + alloc((size_t)NSEG * 4));
    float*          invc   = (float*)(ws + alloc((size_t)NSEG * 4));
    float*          invn   = (float*)(ws + alloc((size_t)NSEG * 4));

    hipMemsetAsync(feat, 0, (size_t)544 * CFEAT * 4, stream);
    hipMemsetAsync(c3, 0, (size_t)NSEG * 3 * 4, stream);

    // one-off weight transpose+convert (independent of segsum)
    k_cvtT<<<dim3(1024 / 32, CFEAT / 32), 256, 0, stream>>>(w1, w1T, CFEAT, 1024);
    k_cvtT<<<dim3(1024 / 32, 1024 / 32), 256, 0, stream>>>(w2, w2T, 1024, 1024);
    k_cvtT<<<dim3(32 / 32, 1024 / 32), 256, 0, stream>>>(w3, w3T, 1024, 32);

    k_counts<<<(PIX + 255) / 256, 256, 0, stream>>>(sp, y, c3);
    k_labels<<<3, 256, 0, stream>>>(c3, lab, invc, out);
    k_segsum_mfma<<<NBLK, 1024, 0, stream>>>(fm, sp, feat);
    k_mean<<<NSEG, 256, 0, stream>>>(feat, featbf, invc, invn);

    gemm_bf16<1><<<dim3(16, 9), 256, 0, stream>>>(featbf, w1T, b1, nullptr, h1bf, NSEG, 1024, CFEAT);
    gemm_bf16<1><<<dim3(16, 9), 256, 0, stream>>>(h1bf, w2T, b2, nullptr, h2bf, NSEG, 1024, 1024);
    gemm_bf16<1><<<dim3(1, 9), 256, 0, stream>>>(h2bf, w3T, b3, h3, nullptr, NSEG, 32, 1024);
    gemm_bf16<0><<<dim3(9, 9), 256, 0, stream>>>(featbf, featbf, nullptr, aff, nullptr, NSEG, NSEG, CFEAT);

    k_head<<<3, 256, 0, stream>>>(h3, wc, bc, out);
    k_prop<<<NSEG, 256, 0, stream>>>(aff, lab, invn, out);
}